// Round 1
// baseline (608.427 us; speedup 1.0000x reference)
//
#include <hip/hip_runtime.h>
#include <math.h>

#define V 32000
#define E 512
#define H 512
#define N 64
#define L 128
#define NV (N*V)
#define NH (N*H)

__device__ __forceinline__ float sigf(float x) { return 1.0f / (1.0f + __expf(-x)); }

// ---------------------------------------------------------------------------
// K1: LSTM gate GEMM, k-split partials.
// gates[n][j] = sum_e emb[n][e]*w_ih[j][e] + sum_k h[n][k]*w_hh[j][k]
// grid (32 j-tiles of 64, 4 k-splits of 256), block 256 = 64 j-lanes x 4 n-groups(16 n)
// ---------------------------------------------------------------------------
__global__ __launch_bounds__(256) void k_gates(
    const int* __restrict__ ids, const float* __restrict__ hprev,
    const float* __restrict__ embW, const float* __restrict__ w_ih,
    const float* __restrict__ w_hh, float* __restrict__ gates_p)
{
    __shared__ __align__(16) float xs[64 * 256];  // 64 KB
    const int bx = blockIdx.x;   // j-tile
    const int ks = blockIdx.y;   // k-split
    const int tid = threadIdx.x;
    const bool emb_part = (ks < 2);
    const int koff = emb_part ? ks * 256 : (ks - 2) * 256;

    // stage x[n][0..255] (emb or h slice), coalesced float4
    for (int i = tid; i < 64 * 64; i += 256) {
        int n = i >> 6, kk4 = i & 63;
        float4 x4;
        if (emb_part)
            x4 = ((const float4*)(embW + (size_t)ids[n] * E + koff))[kk4];
        else
            x4 = ((const float4*)(hprev + (size_t)n * H + koff))[kk4];
        ((float4*)xs)[n * 64 + kk4] = x4;
    }
    __syncthreads();

    const int jl = tid & 63;
    const int ng = tid >> 6;
    const int j = bx * 64 + jl;
    const int nb = ng * 16;
    const float* wrow = (emb_part ? w_ih : w_hh) + (size_t)j * 512 + koff;

    float acc[16];
#pragma unroll
    for (int i = 0; i < 16; ++i) acc[i] = 0.f;

    for (int e4 = 0; e4 < 64; ++e4) {
        float4 w4 = ((const float4*)wrow)[e4];
#pragma unroll
        for (int i = 0; i < 16; ++i) {
            float4 x4 = ((const float4*)xs)[(nb + i) * 64 + e4];  // wave-uniform -> broadcast
            acc[i] += w4.x * x4.x + w4.y * x4.y + w4.z * x4.z + w4.w * x4.w;
        }
    }
#pragma unroll
    for (int i = 0; i < 16; ++i)
        gates_p[(size_t)ks * (64 * 2048) + (size_t)(nb + i) * 2048 + j] = acc[i];
}

// ---------------------------------------------------------------------------
// K1b: combine partials + biases, LSTM pointwise. Writes h_t, c_t into d_out.
// ---------------------------------------------------------------------------
__global__ __launch_bounds__(256) void k_lstm_pw(
    const float* __restrict__ gates_p, const float* __restrict__ b_ih,
    const float* __restrict__ b_hh, const float* __restrict__ cprev,
    float* __restrict__ out)
{
    int i = blockIdx.x * 256 + threadIdx.x;  // 0..32767
    if (i >= NH) return;
    int n = i >> 9, k = i & 511;
    float g[4];
#pragma unroll
    for (int q = 0; q < 4; ++q) {
        int j = q * 512 + k;
        float s = b_ih[j] + b_hh[j];
#pragma unroll
        for (int ks = 0; ks < 4; ++ks)
            s += gates_p[(size_t)ks * (64 * 2048) + (size_t)n * 2048 + j];
        g[q] = s;
    }
    float ig = sigf(g[0]), fg = sigf(g[1]), gg = tanhf(g[2]), og = sigf(g[3]);
    float ct = fg * cprev[i] + ig * gg;
    float ht = og * tanhf(ct);
    out[NV + i] = ht;
    out[NV + NH + i] = ct;
}

// ---------------------------------------------------------------------------
// K2a: sproj = h_t @ Wh.T  (64 x 512, K=512). grid 128, block 256 (one n per 2 blocks)
// ---------------------------------------------------------------------------
__global__ __launch_bounds__(256) void k_sproj(
    const float* __restrict__ out, const float* __restrict__ Wh,
    float* __restrict__ sproj)
{
    __shared__ __align__(16) float xs[512];
    int n = blockIdx.x >> 1;
    int h = (blockIdx.x & 1) * 256 + threadIdx.x;
    const float* ht = out + NV + (size_t)n * 512;
    for (int i = threadIdx.x; i < 512; i += 256) xs[i] = ht[i];
    __syncthreads();
    const float* wrow = Wh + (size_t)h * 512;
    float acc = 0.f;
    for (int e4 = 0; e4 < 128; ++e4) {
        float4 w4 = ((const float4*)wrow)[e4];
        float4 x4 = ((const float4*)xs)[e4];
        acc += w4.x * x4.x + w4.y * x4.y + w4.z * x4.z + w4.w * x4.w;
    }
    sproj[(size_t)n * 512 + h] = acc;
}

// ---------------------------------------------------------------------------
// K2b: score partials. score[n][l] = sum_h tanh(sproj[n][h] + enc[n,l]@Ws[h]) * v[h]
// grid (64 n, 4 h-quarters of 128), block 256 = 64 h-lanes(x2 h) x 4 l-groups(8 l)
// 4 l-chunks of 32 staged in 64 KB LDS. Each wave owns a full h-quarter -> wave reduce.
// ---------------------------------------------------------------------------
__global__ __launch_bounds__(256) void k_score(
    const float* __restrict__ enc, const float* __restrict__ Ws,
    const float* __restrict__ sproj, const float* __restrict__ vvec,
    float* __restrict__ scorep)
{
    __shared__ __align__(16) float es[32 * 512];  // 64 KB
    const int n = blockIdx.x, hq = blockIdx.y;
    const int tid = threadIdx.x;
    const int hl = tid & 63, lg = tid >> 6;
    const int h0 = hq * 128 + hl * 2;
    const float* w0 = Ws + (size_t)h0 * 512;
    const float* w1 = w0 + 512;
    const float sp0 = sproj[(size_t)n * 512 + h0];
    const float sp1 = sproj[(size_t)n * 512 + h0 + 1];
    const float v0 = vvec[h0], v1 = vvec[h0 + 1];

    for (int ch = 0; ch < 4; ++ch) {
        __syncthreads();
        for (int i = tid; i < 32 * 128; i += 256) {
            int l = i >> 7, kk4 = i & 127;
            ((float4*)es)[l * 128 + kk4] =
                ((const float4*)(enc + ((size_t)n * 128 + ch * 32 + l) * 512))[kk4];
        }
        __syncthreads();

        float a0[8], a1[8];
#pragma unroll
        for (int i = 0; i < 8; ++i) { a0[i] = 0.f; a1[i] = 0.f; }

        for (int e4 = 0; e4 < 128; ++e4) {
            float4 wa = ((const float4*)w0)[e4];
            float4 wb = ((const float4*)w1)[e4];
#pragma unroll
            for (int li = 0; li < 8; ++li) {
                float4 x4 = ((const float4*)es)[(lg * 8 + li) * 128 + e4];  // broadcast
                a0[li] += wa.x * x4.x + wa.y * x4.y + wa.z * x4.z + wa.w * x4.w;
                a1[li] += wb.x * x4.x + wb.y * x4.y + wb.z * x4.z + wb.w * x4.w;
            }
        }
#pragma unroll
        for (int li = 0; li < 8; ++li) {
            float t = tanhf(a0[li] + sp0) * v0 + tanhf(a1[li] + sp1) * v1;
#pragma unroll
            for (int off = 32; off > 0; off >>= 1)
                t += __shfl_xor(t, off, 64);
            if (hl == 0)
                scorep[(size_t)hq * (64 * 128) + (size_t)n * 128 + ch * 32 + lg * 8 + li] = t;
        }
    }
}

// ---------------------------------------------------------------------------
// K2c: combine score partials, mask, softmax over L=128, context = attn_w @ enc
// grid 64 (n), block 128
// ---------------------------------------------------------------------------
__global__ __launch_bounds__(128) void k_softmax_ctx(
    const float* __restrict__ scorep, const unsigned char* __restrict__ mask,
    const float* __restrict__ enc, float* __restrict__ ctx)
{
    __shared__ float wl[128];
    __shared__ float red[2];
    const int n = blockIdx.x, t = threadIdx.x;
    float s = scorep[(size_t)n * 128 + t]
            + scorep[8192 + (size_t)n * 128 + t]
            + scorep[2 * 8192 + (size_t)n * 128 + t]
            + scorep[3 * 8192 + (size_t)n * 128 + t];
    if (mask[(size_t)n * 128 + t]) s = -1e30f;

    float m = s;
#pragma unroll
    for (int off = 32; off > 0; off >>= 1) m = fmaxf(m, __shfl_xor(m, off, 64));
    if ((t & 63) == 0) red[t >> 6] = m;
    __syncthreads();
    m = fmaxf(red[0], red[1]);
    __syncthreads();

    float e = __expf(s - m);
    float sum = e;
#pragma unroll
    for (int off = 32; off > 0; off >>= 1) sum += __shfl_xor(sum, off, 64);
    if ((t & 63) == 0) red[t >> 6] = sum;
    __syncthreads();
    sum = red[0] + red[1];
    wl[t] = e / sum;
    __syncthreads();

    float4 acc = make_float4(0.f, 0.f, 0.f, 0.f);
    const float4* encn = (const float4*)(enc + (size_t)n * 128 * 512);
    for (int l = 0; l < 128; ++l) {
        float w = wl[l];
        float4 e4 = encn[l * 128 + t];
        acc.x += w * e4.x; acc.y += w * e4.y; acc.z += w * e4.z; acc.w += w * e4.w;
    }
    ((float4*)(ctx + (size_t)n * 512))[t] = acc;
}

// ---------------------------------------------------------------------------
// K4a: logits = [h_t, ctx] @ h2o_W.T + b. grid 250 (v-tiles of 128),
// block 512 = 64 v-lanes(x2 v) x 8 n-groups(8 n). x staged in 64 KB LDS chunks.
// Writes logits into d_out[0 .. N*V) (normalized in-place by K4b).
// ---------------------------------------------------------------------------
__global__ __launch_bounds__(512) void k_logits(
    const float* __restrict__ out, const float* __restrict__ ctx,
    const float* __restrict__ h2oW, const float* __restrict__ h2ob,
    float* __restrict__ dlogits)
{
    __shared__ __align__(16) float xs[64 * 256];  // 64 KB
    const int tid = threadIdx.x;
    const int vl = tid & 63, ng = tid >> 6;
    const int va = blockIdx.x * 128 + vl * 2;
    const int nb = ng * 8;
    const float* ht = out + NV;

    float acc0[8], acc1[8];
#pragma unroll
    for (int i = 0; i < 8; ++i) { acc0[i] = 0.f; acc1[i] = 0.f; }

    for (int kc = 0; kc < 4; ++kc) {
        __syncthreads();
        for (int i = tid; i < 64 * 64; i += 512) {
            int n = i >> 6, kk4 = i & 63;
            float4 x4;
            if (kc < 2)
                x4 = ((const float4*)(ht + (size_t)n * 512 + kc * 256))[kk4];
            else
                x4 = ((const float4*)(ctx + (size_t)n * 512 + (kc - 2) * 256))[kk4];
            ((float4*)xs)[n * 64 + kk4] = x4;
        }
        __syncthreads();

        const float4* wra = (const float4*)(h2oW + (size_t)va * 1024 + kc * 256);
        const float4* wrb = (const float4*)(h2oW + (size_t)(va + 1) * 1024 + kc * 256);
        for (int e4 = 0; e4 < 64; ++e4) {
            float4 wa = wra[e4];
            float4 wb = wrb[e4];
#pragma unroll
            for (int i = 0; i < 8; ++i) {
                float4 x4 = ((const float4*)xs)[(nb + i) * 64 + e4];  // broadcast
                acc0[i] += wa.x * x4.x + wa.y * x4.y + wa.z * x4.z + wa.w * x4.w;
                acc1[i] += wb.x * x4.x + wb.y * x4.y + wb.z * x4.z + wb.w * x4.w;
            }
        }
    }
    float ba = h2ob[va], bb = h2ob[va + 1];
#pragma unroll
    for (int i = 0; i < 8; ++i) {
        dlogits[(size_t)(nb + i) * V + va]     = acc0[i] + ba;
        dlogits[(size_t)(nb + i) * V + va + 1] = acc1[i] + bb;
    }
}

// ---------------------------------------------------------------------------
// K4b: in-place log-softmax over V per row. grid 64, block 256.
// ---------------------------------------------------------------------------
__global__ __launch_bounds__(256) void k_logsoftmax(float* __restrict__ dout)
{
    __shared__ float red[4];
    const int n = blockIdx.x, t = threadIdx.x;
    float* row = dout + (size_t)n * V;
    float m = -1e30f;
    for (int i = t; i < V; i += 256) m = fmaxf(m, row[i]);
#pragma unroll
    for (int off = 32; off > 0; off >>= 1) m = fmaxf(m, __shfl_xor(m, off, 64));
    if ((t & 63) == 0) red[t >> 6] = m;
    __syncthreads();
    m = fmaxf(fmaxf(red[0], red[1]), fmaxf(red[2], red[3]));
    __syncthreads();
    float s = 0.f;
    for (int i = t; i < V; i += 256) s += __expf(row[i] - m);
#pragma unroll
    for (int off = 32; off > 0; off >>= 1) s += __shfl_xor(s, off, 64);
    if ((t & 63) == 0) red[t >> 6] = s;
    __syncthreads();
    s = red[0] + red[1] + red[2] + red[3];
    float lse = m + __logf(s);
    for (int i = t; i < V; i += 256) row[i] = row[i] - lse;
}

// ---------------------------------------------------------------------------
extern "C" void kernel_launch(void* const* d_in, const int* in_sizes, int n_in,
                              void* d_out, int out_size, void* d_ws, size_t ws_size,
                              hipStream_t stream)
{
    const int* ids   = (const int*)d_in[0];
    const float* h   = (const float*)d_in[1];
    const float* c   = (const float*)d_in[2];
    const float* enc = (const float*)d_in[3];
    const unsigned char* mask = (const unsigned char*)d_in[4];
    const float* embW = (const float*)d_in[5];
    const float* w_ih = (const float*)d_in[6];
    const float* b_ih = (const float*)d_in[7];
    const float* w_hh = (const float*)d_in[8];
    const float* b_hh = (const float*)d_in[9];
    const float* Wh   = (const float*)d_in[10];
    const float* Ws   = (const float*)d_in[11];
    const float* av   = (const float*)d_in[12];
    const float* h2oW = (const float*)d_in[13];
    const float* h2ob = (const float*)d_in[14];

    float* out = (float*)d_out;
    float* ws = (float*)d_ws;
    float* gates_p = ws;              // 4*64*2048 = 524288 floats
    float* sproj   = ws + 524288;     // 32768
    float* scorep  = ws + 557056;     // 4*64*128 = 32768
    float* ctx     = ws + 589824;     // 32768

    k_gates<<<dim3(32, 4), 256, 0, stream>>>(ids, h, embW, w_ih, w_hh, gates_p);
    k_lstm_pw<<<128, 256, 0, stream>>>(gates_p, b_ih, b_hh, c, out);
    k_sproj<<<128, 256, 0, stream>>>(out, Wh, sproj);
    k_score<<<dim3(64, 4), 256, 0, stream>>>(enc, Ws, sproj, av, scorep);
    k_softmax_ctx<<<64, 128, 0, stream>>>(scorep, mask, enc, ctx);
    k_logits<<<250, 512, 0, stream>>>(out, ctx, h2oW, h2ob, out);
    k_logsoftmax<<<64, 256, 0, stream>>>(out);
}

// Round 2
// 459.487 us; speedup vs baseline: 1.3241x; 1.3241x over previous
//
#include <hip/hip_runtime.h>
#include <math.h>

#define V 32000
#define E 512
#define H 512
#define N 64
#define L 128
#define NV (N*V)
#define NH (N*H)
#define MTOT (N*L)   // 8192 rows of the score GEMM

typedef short  s8v  __attribute__((ext_vector_type(8)));   // 8 bf16 (4 VGPRs)
typedef float  f4v  __attribute__((ext_vector_type(4)));

__device__ __forceinline__ float sigf(float x) { return 1.0f / (1.0f + __expf(-x)); }

// fp32 -> bf16 round-to-nearest-even
__device__ __forceinline__ unsigned short f2bf(float f) {
    unsigned int u = __float_as_uint(f);
    unsigned int r = u + 0x7FFFu + ((u >> 16) & 1u);
    return (unsigned short)(r >> 16);
}

// ---------------------------------------------------------------------------
// K1: LSTM gate GEMM, k-split partials. grid (32 j-tiles, 8 k-splits of 128),
// block 256 = 64 j-lanes x 4 n-groups(16 n). LDS 32 KB -> better occupancy.
// ---------------------------------------------------------------------------
__global__ __launch_bounds__(256) void k_gates(
    const int* __restrict__ ids, const float* __restrict__ hprev,
    const float* __restrict__ embW, const float* __restrict__ w_ih,
    const float* __restrict__ w_hh, float* __restrict__ gates_p)
{
    __shared__ __align__(16) float xs[64 * 128];  // 32 KB
    const int bx = blockIdx.x;   // j-tile
    const int ks = blockIdx.y;   // k-split (0..7): 0-3 emb, 4-7 h
    const int tid = threadIdx.x;
    const bool emb_part = (ks < 4);
    const int koff = (ks & 3) * 128;

    for (int i = tid; i < 64 * 32; i += 256) {
        int n = i >> 5, kk4 = i & 31;
        float4 x4;
        if (emb_part)
            x4 = ((const float4*)(embW + (size_t)ids[n] * E + koff))[kk4];
        else
            x4 = ((const float4*)(hprev + (size_t)n * H + koff))[kk4];
        ((float4*)xs)[n * 32 + kk4] = x4;
    }
    __syncthreads();

    const int jl = tid & 63;
    const int ng = tid >> 6;
    const int j = bx * 64 + jl;
    const int nb = ng * 16;
    const float* wrow = (emb_part ? w_ih : w_hh) + (size_t)j * 512 + koff;

    float acc[16];
#pragma unroll
    for (int i = 0; i < 16; ++i) acc[i] = 0.f;

    for (int e4 = 0; e4 < 32; ++e4) {
        float4 w4 = ((const float4*)wrow)[e4];
#pragma unroll
        for (int i = 0; i < 16; ++i) {
            float4 x4 = ((const float4*)xs)[(nb + i) * 32 + e4];  // wave-uniform broadcast
            acc[i] += w4.x * x4.x + w4.y * x4.y + w4.z * x4.z + w4.w * x4.w;
        }
    }
#pragma unroll
    for (int i = 0; i < 16; ++i)
        gates_p[(size_t)ks * (64 * 2048) + (size_t)(nb + i) * 2048 + j] = acc[i];
}

// ---------------------------------------------------------------------------
// K1b: combine partials + biases, LSTM pointwise. Writes h_t, c_t into d_out.
// ---------------------------------------------------------------------------
__global__ __launch_bounds__(256) void k_lstm_pw(
    const float* __restrict__ gates_p, const float* __restrict__ b_ih,
    const float* __restrict__ b_hh, const float* __restrict__ cprev,
    float* __restrict__ out)
{
    int i = blockIdx.x * 256 + threadIdx.x;  // 0..32767
    if (i >= NH) return;
    int n = i >> 9, k = i & 511;
    float g[4];
#pragma unroll
    for (int q = 0; q < 4; ++q) {
        int j = q * 512 + k;
        float s = b_ih[j] + b_hh[j];
#pragma unroll
        for (int ks = 0; ks < 8; ++ks)
            s += gates_p[(size_t)ks * (64 * 2048) + (size_t)n * 2048 + j];
        g[q] = s;
    }
    float ig = sigf(g[0]), fg = sigf(g[1]), gg = tanhf(g[2]), og = sigf(g[3]);
    float ct = fg * cprev[i] + ig * gg;
    float ht = og * tanhf(ct);
    out[NV + i] = ht;
    out[NV + NH + i] = ct;
}

// ---------------------------------------------------------------------------
// K2a: sproj = h_t @ Wh.T  (64 x 512, K=512). grid 128, block 256.
// ---------------------------------------------------------------------------
__global__ __launch_bounds__(256) void k_sproj(
    const float* __restrict__ out, const float* __restrict__ Wh,
    float* __restrict__ sproj)
{
    __shared__ __align__(16) float xs[512];
    int n = blockIdx.x >> 1;
    int h = (blockIdx.x & 1) * 256 + threadIdx.x;
    const float* ht = out + NV + (size_t)n * 512;
    for (int i = threadIdx.x; i < 512; i += 256) xs[i] = ht[i];
    __syncthreads();
    const float* wrow = Wh + (size_t)h * 512;
    float acc = 0.f;
    for (int e4 = 0; e4 < 128; ++e4) {
        float4 w4 = ((const float4*)wrow)[e4];
        float4 x4 = ((const float4*)xs)[e4];
        acc += w4.x * x4.x + w4.y * x4.y + w4.z * x4.z + w4.w * x4.w;
    }
    sproj[(size_t)n * 512 + h] = acc;
}

// ---------------------------------------------------------------------------
// K2b: score GEMM via bf16 MFMA.  proj_pre = enc @ Ws^T  (M=8192, N=512, K=512)
// fused epilogue: score_partial[bh][m] = sum_{h in tile} tanh(proj+sproj)*v[h]
// grid (128 m-tiles, 8 h-tiles), block 256 = 4 waves in 2x2; tile 64x64, BK=64.
// A,B staged fp32->bf16 on the fly; LDS rows padded to 72 bf16 (16B-aligned,
// conflict-free for both b128 reads and writes).
// ---------------------------------------------------------------------------
__global__ __launch_bounds__(256) void k_score_gemm(
    const float* __restrict__ enc, const float* __restrict__ Ws,
    const float* __restrict__ sproj, const float* __restrict__ av,
    float* __restrict__ scorep)
{
    __shared__ __align__(16) short As[64 * 72];  // 9216 B
    __shared__ __align__(16) short Bs[64 * 72];  // 9216 B
    __shared__ float sred[64];

    const int bm = blockIdx.x, bh = blockIdx.y;
    const int tid = threadIdx.x;
    const int w = tid >> 6, l = tid & 63;
    const int wave_m = (w >> 1) * 32, wave_h = (w & 1) * 32;
    const int lq = l >> 4, lr = l & 15;

    if (tid < 64) sred[tid] = 0.f;

    f4v acc[2][2];
#pragma unroll
    for (int i = 0; i < 2; ++i)
#pragma unroll
        for (int j = 0; j < 2; ++j) acc[i][j] = (f4v)0.f;

    for (int kt = 0; kt < 8; ++kt) {
        __syncthreads();
        // stage A (enc tile) and B (Ws tile), 8 bf16 per thread per round
#pragma unroll
        for (int r = 0; r < 2; ++r) {
            int idx = (r * 256 + tid) * 8;
            int row = idx >> 6, col = idx & 63;
            const float* sa = enc + (size_t)(bm * 64 + row) * 512 + kt * 64 + col;
            const float* sb = Ws  + (size_t)(bh * 64 + row) * 512 + kt * 64 + col;
            float4 a0 = *(const float4*)sa, a1 = *(const float4*)(sa + 4);
            float4 b0 = *(const float4*)sb, b1 = *(const float4*)(sb + 4);
            union { unsigned short u[8]; uint4 q; } pa, pb;
            pa.u[0]=f2bf(a0.x); pa.u[1]=f2bf(a0.y); pa.u[2]=f2bf(a0.z); pa.u[3]=f2bf(a0.w);
            pa.u[4]=f2bf(a1.x); pa.u[5]=f2bf(a1.y); pa.u[6]=f2bf(a1.z); pa.u[7]=f2bf(a1.w);
            pb.u[0]=f2bf(b0.x); pb.u[1]=f2bf(b0.y); pb.u[2]=f2bf(b0.z); pb.u[3]=f2bf(b0.w);
            pb.u[4]=f2bf(b1.x); pb.u[5]=f2bf(b1.y); pb.u[6]=f2bf(b1.z); pb.u[7]=f2bf(b1.w);
            *(uint4*)(As + row * 72 + col) = pa.q;
            *(uint4*)(Bs + row * 72 + col) = pb.q;
        }
        __syncthreads();

#pragma unroll
        for (int ks = 0; ks < 2; ++ks) {
            s8v a_frag[2], b_frag[2];
#pragma unroll
            for (int i = 0; i < 2; ++i)
                a_frag[i] = *(const s8v*)(As + (wave_m + 16 * i + lr) * 72 + ks * 32 + lq * 8);
#pragma unroll
            for (int j = 0; j < 2; ++j)
                b_frag[j] = *(const s8v*)(Bs + (wave_h + 16 * j + lr) * 72 + ks * 32 + lq * 8);
#pragma unroll
            for (int i = 0; i < 2; ++i)
#pragma unroll
                for (int j = 0; j < 2; ++j)
                    acc[i][j] = __builtin_amdgcn_mfma_f32_16x16x32_bf16(
                        a_frag[i], b_frag[j], acc[i][j], 0, 0, 0);
        }
    }
    __syncthreads();

    // epilogue: tanh(proj + sproj)*v, reduce over this block's 64 h-columns
    const int hc0 = bh * 64 + wave_h + lr;
#pragma unroll
    for (int i = 0; i < 2; ++i) {
#pragma unroll
        for (int reg = 0; reg < 4; ++reg) {
            int m_local = wave_m + 16 * i + lq * 4 + reg;
            int m = bm * 64 + m_local;
            int n = m >> 7;
            float p = 0.f;
#pragma unroll
            for (int j = 0; j < 2; ++j) {
                int hc = hc0 + 16 * j;
                float val = acc[i][j][reg] + sproj[(size_t)n * 512 + hc];
                p += tanhf(val) * av[hc];
            }
            // reduce across the 16 lanes (lr) of this quad
            p += __shfl_xor(p, 1, 64);
            p += __shfl_xor(p, 2, 64);
            p += __shfl_xor(p, 4, 64);
            p += __shfl_xor(p, 8, 64);
            if (lr == 0) atomicAdd(&sred[m_local], p);
        }
    }
    __syncthreads();
    if (tid < 64)
        scorep[(size_t)bh * MTOT + bm * 64 + tid] = sred[tid];
}

// ---------------------------------------------------------------------------
// K2c: combine 8 score partials, mask, softmax over L=128, context = attn_w@enc
// grid 64 (n), block 512 (coalesced context phase)
// ---------------------------------------------------------------------------
__global__ __launch_bounds__(512) void k_softmax_ctx(
    const float* __restrict__ scorep, const unsigned char* __restrict__ mask,
    const float* __restrict__ enc, float* __restrict__ ctx)
{
    __shared__ float sc[128];
    __shared__ float wl[128];
    const int n = blockIdx.x, t = threadIdx.x;

    if (t < 128) {
        float s = 0.f;
#pragma unroll
        for (int q = 0; q < 8; ++q)
            s += scorep[(size_t)q * MTOT + n * 128 + t];
        if (mask[(size_t)n * 128 + t]) s = -1e30f;
        sc[t] = s;
    }
    __syncthreads();
    if (t < 64) {  // one full wave
        float m = fmaxf(sc[t], sc[t + 64]);
#pragma unroll
        for (int off = 32; off > 0; off >>= 1) m = fmaxf(m, __shfl_xor(m, off, 64));
        float e0 = __expf(sc[t] - m), e1 = __expf(sc[t + 64] - m);
        float ss = e0 + e1;
#pragma unroll
        for (int off = 32; off > 0; off >>= 1) ss += __shfl_xor(ss, off, 64);
        float inv = 1.0f / ss;
        wl[t] = e0 * inv;
        wl[t + 64] = e1 * inv;
    }
    __syncthreads();

    const float* encn = enc + (size_t)n * L * H + t;
    float acc = 0.f;
#pragma unroll 4
    for (int ll = 0; ll < 128; ++ll)
        acc += wl[ll] * encn[(size_t)ll * 512];
    ctx[(size_t)n * 512 + t] = acc;
}

// ---------------------------------------------------------------------------
// K4a: logits = [h_t, ctx] @ h2o_W.T + b. grid 500 (v-tiles of 64), block 512
// = 64 v-lanes x 8 n-groups(8 n). 32 KB LDS chunks -> 2 blocks/CU, 16 waves.
// ---------------------------------------------------------------------------
__global__ __launch_bounds__(512) void k_logits(
    const float* __restrict__ out, const float* __restrict__ ctx,
    const float* __restrict__ h2oW, const float* __restrict__ h2ob,
    float* __restrict__ dlogits)
{
    __shared__ __align__(16) float xs[64 * 128];  // 32 KB
    const int tid = threadIdx.x;
    const int vl = tid & 63, ng = tid >> 6;
    const int v = blockIdx.x * 64 + vl;
    const int nb = ng * 8;
    const float* ht = out + NV;

    float acc[8];
#pragma unroll
    for (int i = 0; i < 8; ++i) acc[i] = 0.f;

    for (int kc = 0; kc < 8; ++kc) {
        __syncthreads();
        for (int i = tid; i < 64 * 32; i += 512) {
            int n = i >> 5, kk4 = i & 31;
            float4 x4;
            if (kc < 4)
                x4 = ((const float4*)(ht + (size_t)n * 512 + kc * 128))[kk4];
            else
                x4 = ((const float4*)(ctx + (size_t)n * 512 + (kc - 4) * 128))[kk4];
            ((float4*)xs)[n * 32 + kk4] = x4;
        }
        __syncthreads();

        const float4* wr = (const float4*)(h2oW + (size_t)v * 1024 + kc * 128);
        for (int e4 = 0; e4 < 32; ++e4) {
            float4 w4 = wr[e4];
#pragma unroll
            for (int i = 0; i < 8; ++i) {
                float4 x4 = ((const float4*)xs)[(nb + i) * 32 + e4];  // broadcast
                acc[i] += w4.x * x4.x + w4.y * x4.y + w4.z * x4.z + w4.w * x4.w;
            }
        }
    }
    float bv = h2ob[v];
#pragma unroll
    for (int i = 0; i < 8; ++i)
        dlogits[(size_t)(nb + i) * V + v] = acc[i] + bv;
}

// ---------------------------------------------------------------------------
// K4b: in-place log-softmax over V per row. grid 64, block 256.
// ---------------------------------------------------------------------------
__global__ __launch_bounds__(256) void k_logsoftmax(float* __restrict__ dout)
{
    __shared__ float red[4];
    const int n = blockIdx.x, t = threadIdx.x;
    float* row = dout + (size_t)n * V;
    float m = -1e30f;
    for (int i = t; i < V; i += 256) m = fmaxf(m, row[i]);
#pragma unroll
    for (int off = 32; off > 0; off >>= 1) m = fmaxf(m, __shfl_xor(m, off, 64));
    if ((t & 63) == 0) red[t >> 6] = m;
    __syncthreads();
    m = fmaxf(fmaxf(red[0], red[1]), fmaxf(red[2], red[3]));
    __syncthreads();
    float s = 0.f;
    for (int i = t; i < V; i += 256) s += __expf(row[i] - m);
#pragma unroll
    for (int off = 32; off > 0; off >>= 1) s += __shfl_xor(s, off, 64);
    if ((t & 63) == 0) red[t >> 6] = s;
    __syncthreads();
    s = red[0] + red[1] + red[2] + red[3];
    float lse = m + __logf(s);
    for (int i = t; i < V; i += 256) row[i] = row[i] - lse;
}

// ---------------------------------------------------------------------------
extern "C" void kernel_launch(void* const* d_in, const int* in_sizes, int n_in,
                              void* d_out, int out_size, void* d_ws, size_t ws_size,
                              hipStream_t stream)
{
    const int* ids   = (const int*)d_in[0];
    const float* h   = (const float*)d_in[1];
    const float* c   = (const float*)d_in[2];
    const float* enc = (const float*)d_in[3];
    const unsigned char* mask = (const unsigned char*)d_in[4];
    const float* embW = (const float*)d_in[5];
    const float* w_ih = (const float*)d_in[6];
    const float* b_ih = (const float*)d_in[7];
    const float* w_hh = (const float*)d_in[8];
    const float* b_hh = (const float*)d_in[9];
    const float* Wh   = (const float*)d_in[10];
    const float* Ws   = (const float*)d_in[11];
    const float* av   = (const float*)d_in[12];
    const float* h2oW = (const float*)d_in[13];
    const float* h2ob = (const float*)d_in[14];

    float* out = (float*)d_out;
    float* ws = (float*)d_ws;
    float* gates_p = ws;                  // 8*64*2048 = 1048576 floats (4 MB)
    float* sproj   = ws + 1048576;        // 32768
    float* scorep  = ws + 1048576 + 32768;          // 8*8192 = 65536
    float* ctx     = ws + 1048576 + 32768 + 65536;  // 32768

    k_gates<<<dim3(32, 8), 256, 0, stream>>>(ids, h, embW, w_ih, w_hh, gates_p);
    k_lstm_pw<<<128, 256, 0, stream>>>(gates_p, b_ih, b_hh, c, out);
    k_sproj<<<128, 256, 0, stream>>>(out, Wh, sproj);
    k_score_gemm<<<dim3(128, 8), 256, 0, stream>>>(enc, Ws, sproj, av, scorep);
    k_softmax_ctx<<<64, 512, 0, stream>>>(scorep, mask, enc, ctx);
    k_logits<<<500, 512, 0, stream>>>(out, ctx, h2oW, h2ob, out);
    k_logsoftmax<<<64, 256, 0, stream>>>(out);
}

// Round 3
// 348.452 us; speedup vs baseline: 1.7461x; 1.3187x over previous
//
#include <hip/hip_runtime.h>
#include <math.h>

#define V 32000
#define E 512
#define H 512
#define N 64
#define L 128
#define NV (N*V)
#define NH (N*H)
#define MTOT (N*L)   // 8192 rows of the score GEMM
#define VT 500       // v-tiles (of 64) in k_logits

typedef short  s8v  __attribute__((ext_vector_type(8)));   // 8 bf16 (4 VGPRs)
typedef float  f4v  __attribute__((ext_vector_type(4)));

__device__ __forceinline__ float sigf(float x) { return 1.0f / (1.0f + __expf(-x)); }

// fp32 -> bf16 round-to-nearest-even
__device__ __forceinline__ unsigned short f2bf(float f) {
    unsigned int u = __float_as_uint(f);
    unsigned int r = u + 0x7FFFu + ((u >> 16) & 1u);
    return (unsigned short)(r >> 16);
}

// ---------------------------------------------------------------------------
// K1: LSTM gate GEMM, k-split partials. grid (32 j-tiles, 8 k-splits of 128),
// block 256 = 64 j-lanes x 4 n-groups(16 n). LDS 32 KB.
// ---------------------------------------------------------------------------
__global__ __launch_bounds__(256) void k_gates(
    const int* __restrict__ ids, const float* __restrict__ hprev,
    const float* __restrict__ embW, const float* __restrict__ w_ih,
    const float* __restrict__ w_hh, float* __restrict__ gates_p)
{
    __shared__ __align__(16) float xs[64 * 128];  // 32 KB
    const int bx = blockIdx.x;   // j-tile
    const int ks = blockIdx.y;   // k-split (0..7): 0-3 emb, 4-7 h
    const int tid = threadIdx.x;
    const bool emb_part = (ks < 4);
    const int koff = (ks & 3) * 128;

    for (int i = tid; i < 64 * 32; i += 256) {
        int n = i >> 5, kk4 = i & 31;
        float4 x4;
        if (emb_part)
            x4 = ((const float4*)(embW + (size_t)ids[n] * E + koff))[kk4];
        else
            x4 = ((const float4*)(hprev + (size_t)n * H + koff))[kk4];
        ((float4*)xs)[n * 32 + kk4] = x4;
    }
    __syncthreads();

    const int jl = tid & 63;
    const int ng = tid >> 6;
    const int j = bx * 64 + jl;
    const int nb = ng * 16;
    const float* wrow = (emb_part ? w_ih : w_hh) + (size_t)j * 512 + koff;

    float acc[16];
#pragma unroll
    for (int i = 0; i < 16; ++i) acc[i] = 0.f;

    for (int e4 = 0; e4 < 32; ++e4) {
        float4 w4 = ((const float4*)wrow)[e4];
#pragma unroll
        for (int i = 0; i < 16; ++i) {
            float4 x4 = ((const float4*)xs)[(nb + i) * 32 + e4];  // wave-uniform broadcast
            acc[i] += w4.x * x4.x + w4.y * x4.y + w4.z * x4.z + w4.w * x4.w;
        }
    }
#pragma unroll
    for (int i = 0; i < 16; ++i)
        gates_p[(size_t)ks * (64 * 2048) + (size_t)(nb + i) * 2048 + j] = acc[i];
}

// ---------------------------------------------------------------------------
// K1b: combine partials + biases, LSTM pointwise. Writes h_t, c_t into d_out
// and bf16 h_t into xb[:, 0:512].
// ---------------------------------------------------------------------------
__global__ __launch_bounds__(256) void k_lstm_pw(
    const float* __restrict__ gates_p, const float* __restrict__ b_ih,
    const float* __restrict__ b_hh, const float* __restrict__ cprev,
    float* __restrict__ out, unsigned short* __restrict__ xb)
{
    int i = blockIdx.x * 256 + threadIdx.x;  // 0..32767
    if (i >= NH) return;
    int n = i >> 9, k = i & 511;
    float g[4];
#pragma unroll
    for (int q = 0; q < 4; ++q) {
        int j = q * 512 + k;
        float s = b_ih[j] + b_hh[j];
#pragma unroll
        for (int ks = 0; ks < 8; ++ks)
            s += gates_p[(size_t)ks * (64 * 2048) + (size_t)n * 2048 + j];
        g[q] = s;
    }
    float ig = sigf(g[0]), fg = sigf(g[1]), gg = tanhf(g[2]), og = sigf(g[3]);
    float ct = fg * cprev[i] + ig * gg;
    float ht = og * tanhf(ct);
    out[NV + i] = ht;
    out[NV + NH + i] = ct;
    xb[(size_t)n * 1024 + k] = f2bf(ht);
}

// ---------------------------------------------------------------------------
// K2a: sproj = h_t @ Wh.T  (64 x 512, K=512). grid 128, block 256.
// ---------------------------------------------------------------------------
__global__ __launch_bounds__(256) void k_sproj(
    const float* __restrict__ out, const float* __restrict__ Wh,
    float* __restrict__ sproj)
{
    __shared__ __align__(16) float xs[512];
    int n = blockIdx.x >> 1;
    int h = (blockIdx.x & 1) * 256 + threadIdx.x;
    const float* ht = out + NV + (size_t)n * 512;
    for (int i = threadIdx.x; i < 512; i += 256) xs[i] = ht[i];
    __syncthreads();
    const float* wrow = Wh + (size_t)h * 512;
    float acc = 0.f;
    for (int e4 = 0; e4 < 128; ++e4) {
        float4 w4 = ((const float4*)wrow)[e4];
        float4 x4 = ((const float4*)xs)[e4];
        acc += w4.x * x4.x + w4.y * x4.y + w4.z * x4.z + w4.w * x4.w;
    }
    sproj[(size_t)n * 512 + h] = acc;
}

// ---------------------------------------------------------------------------
// K2b: score GEMM via bf16 MFMA + fused tanh/v-dot epilogue (unchanged from R1).
// grid (128 m-tiles, 8 h-tiles), block 256.
// ---------------------------------------------------------------------------
__global__ __launch_bounds__(256) void k_score_gemm(
    const float* __restrict__ enc, const float* __restrict__ Ws,
    const float* __restrict__ sproj, const float* __restrict__ av,
    float* __restrict__ scorep)
{
    __shared__ __align__(16) short As[64 * 72];
    __shared__ __align__(16) short Bs[64 * 72];
    __shared__ float sred[64];

    const int bm = blockIdx.x, bh = blockIdx.y;
    const int tid = threadIdx.x;
    const int w = tid >> 6, l = tid & 63;
    const int wave_m = (w >> 1) * 32, wave_h = (w & 1) * 32;
    const int lq = l >> 4, lr = l & 15;

    if (tid < 64) sred[tid] = 0.f;

    f4v acc[2][2];
#pragma unroll
    for (int i = 0; i < 2; ++i)
#pragma unroll
        for (int j = 0; j < 2; ++j) acc[i][j] = (f4v)0.f;

    for (int kt = 0; kt < 8; ++kt) {
        __syncthreads();
#pragma unroll
        for (int r = 0; r < 2; ++r) {
            int idx = (r * 256 + tid) * 8;
            int row = idx >> 6, col = idx & 63;
            const float* sa = enc + (size_t)(bm * 64 + row) * 512 + kt * 64 + col;
            const float* sb = Ws  + (size_t)(bh * 64 + row) * 512 + kt * 64 + col;
            float4 a0 = *(const float4*)sa, a1 = *(const float4*)(sa + 4);
            float4 b0 = *(const float4*)sb, b1 = *(const float4*)(sb + 4);
            union { unsigned short u[8]; uint4 q; } pa, pb;
            pa.u[0]=f2bf(a0.x); pa.u[1]=f2bf(a0.y); pa.u[2]=f2bf(a0.z); pa.u[3]=f2bf(a0.w);
            pa.u[4]=f2bf(a1.x); pa.u[5]=f2bf(a1.y); pa.u[6]=f2bf(a1.z); pa.u[7]=f2bf(a1.w);
            pb.u[0]=f2bf(b0.x); pb.u[1]=f2bf(b0.y); pb.u[2]=f2bf(b0.z); pb.u[3]=f2bf(b0.w);
            pb.u[4]=f2bf(b1.x); pb.u[5]=f2bf(b1.y); pb.u[6]=f2bf(b1.z); pb.u[7]=f2bf(b1.w);
            *(uint4*)(As + row * 72 + col) = pa.q;
            *(uint4*)(Bs + row * 72 + col) = pb.q;
        }
        __syncthreads();

#pragma unroll
        for (int ks = 0; ks < 2; ++ks) {
            s8v a_frag[2], b_frag[2];
#pragma unroll
            for (int i = 0; i < 2; ++i)
                a_frag[i] = *(const s8v*)(As + (wave_m + 16 * i + lr) * 72 + ks * 32 + lq * 8);
#pragma unroll
            for (int j = 0; j < 2; ++j)
                b_frag[j] = *(const s8v*)(Bs + (wave_h + 16 * j + lr) * 72 + ks * 32 + lq * 8);
#pragma unroll
            for (int i = 0; i < 2; ++i)
#pragma unroll
                for (int j = 0; j < 2; ++j)
                    acc[i][j] = __builtin_amdgcn_mfma_f32_16x16x32_bf16(
                        a_frag[i], b_frag[j], acc[i][j], 0, 0, 0);
        }
    }
    __syncthreads();

    const int hc0 = bh * 64 + wave_h + lr;
#pragma unroll
    for (int i = 0; i < 2; ++i) {
#pragma unroll
        for (int reg = 0; reg < 4; ++reg) {
            int m_local = wave_m + 16 * i + lq * 4 + reg;
            int m = bm * 64 + m_local;
            int n = m >> 7;
            float p = 0.f;
#pragma unroll
            for (int j = 0; j < 2; ++j) {
                int hc = hc0 + 16 * j;
                float val = acc[i][j][reg] + sproj[(size_t)n * 512 + hc];
                p += tanhf(val) * av[hc];
            }
            p += __shfl_xor(p, 1, 64);
            p += __shfl_xor(p, 2, 64);
            p += __shfl_xor(p, 4, 64);
            p += __shfl_xor(p, 8, 64);
            if (lr == 0) atomicAdd(&sred[m_local], p);
        }
    }
    __syncthreads();
    if (tid < 64)
        scorep[(size_t)bh * MTOT + bm * 64 + tid] = sred[tid];
}

// ---------------------------------------------------------------------------
// K2c: combine score partials, mask, softmax over L, context; writes bf16
// context into xb[:, 512:1024]. grid 64 (n), block 512.
// ---------------------------------------------------------------------------
__global__ __launch_bounds__(512) void k_softmax_ctx(
    const float* __restrict__ scorep, const unsigned char* __restrict__ mask,
    const float* __restrict__ enc, unsigned short* __restrict__ xb)
{
    __shared__ float sc[128];
    __shared__ float wl[128];
    const int n = blockIdx.x, t = threadIdx.x;

    if (t < 128) {
        float s = 0.f;
#pragma unroll
        for (int q = 0; q < 8; ++q)
            s += scorep[(size_t)q * MTOT + n * 128 + t];
        if (mask[(size_t)n * 128 + t]) s = -1e30f;
        sc[t] = s;
    }
    __syncthreads();
    if (t < 64) {
        float m = fmaxf(sc[t], sc[t + 64]);
#pragma unroll
        for (int off = 32; off > 0; off >>= 1) m = fmaxf(m, __shfl_xor(m, off, 64));
        float e0 = __expf(sc[t] - m), e1 = __expf(sc[t + 64] - m);
        float ss = e0 + e1;
#pragma unroll
        for (int off = 32; off > 0; off >>= 1) ss += __shfl_xor(ss, off, 64);
        float inv = 1.0f / ss;
        wl[t] = e0 * inv;
        wl[t + 64] = e1 * inv;
    }
    __syncthreads();

    const float* encn = enc + (size_t)n * L * H + t;
    float acc = 0.f;
#pragma unroll 4
    for (int ll = 0; ll < 128; ++ll)
        acc += wl[ll] * encn[(size_t)ll * 512];
    xb[(size_t)n * 1024 + 512 + t] = f2bf(acc);
}

// ---------------------------------------------------------------------------
// K4a: logits GEMM via bf16 MFMA, C^T view: M=v(32000), N=n(64), K=1024.
// grid 500 (v-tiles of 64), block 256 = 4 waves (2x2 of 32x32). BK=64.
// Weights fp32->bf16 staged with register prefetch across the barrier.
// Epilogue: LDS transpose -> coalesced fp32 stores + per-block log-softmax
// partials (max, sumexp) per row n.
// ---------------------------------------------------------------------------
__global__ __launch_bounds__(256) void k_logits(
    const float* __restrict__ h2oW, const unsigned short* __restrict__ xb,
    const float* __restrict__ h2ob, float* __restrict__ dlogits,
    float* __restrict__ pmax, float* __restrict__ psum)
{
    __shared__ __align__(16) short As[64 * 72];   //  9216 B (v x k)
    __shared__ __align__(16) short Bs[64 * 72];   //  9216 B (n x k)
    __shared__ __align__(16) float cs[64 * 68];   // 17408 B (n x v)

    const int bm = blockIdx.x;   // v-tile
    const int tid = threadIdx.x;
    const int w = tid >> 6, l = tid & 63;
    const int wave_m = (w & 1) * 32, wave_n = (w >> 1) * 32;
    const int lq = l >> 4, lr = l & 15;

    const int arow = tid >> 2;            // 0..63
    const int acol = (tid & 3) * 16;      // 0,16,32,48
    const float* aptr = h2oW + (size_t)(bm * 64 + arow) * 1024 + acol;
    const unsigned short* bptr = xb + (size_t)arow * 1024 + acol;

    f4v acc[2][2];
#pragma unroll
    for (int i = 0; i < 2; ++i)
#pragma unroll
        for (int j = 0; j < 2; ++j) acc[i][j] = (f4v)0.f;

    float4 ra[4];
    uint4  rb[2];
#pragma unroll
    for (int r = 0; r < 4; ++r) ra[r] = ((const float4*)aptr)[r];
    rb[0] = *(const uint4*)bptr;
    rb[1] = *(const uint4*)(bptr + 8);

#pragma unroll 1
    for (int kt = 0; kt < 16; ++kt) {
        if (kt) __syncthreads();
        union { unsigned short u[8]; uint4 q; } p0, p1;
        p0.u[0]=f2bf(ra[0].x); p0.u[1]=f2bf(ra[0].y); p0.u[2]=f2bf(ra[0].z); p0.u[3]=f2bf(ra[0].w);
        p0.u[4]=f2bf(ra[1].x); p0.u[5]=f2bf(ra[1].y); p0.u[6]=f2bf(ra[1].z); p0.u[7]=f2bf(ra[1].w);
        p1.u[0]=f2bf(ra[2].x); p1.u[1]=f2bf(ra[2].y); p1.u[2]=f2bf(ra[2].z); p1.u[3]=f2bf(ra[2].w);
        p1.u[4]=f2bf(ra[3].x); p1.u[5]=f2bf(ra[3].y); p1.u[6]=f2bf(ra[3].z); p1.u[7]=f2bf(ra[3].w);
        *(uint4*)(As + arow * 72 + acol)     = p0.q;
        *(uint4*)(As + arow * 72 + acol + 8) = p1.q;
        *(uint4*)(Bs + arow * 72 + acol)     = rb[0];
        *(uint4*)(Bs + arow * 72 + acol + 8) = rb[1];
        __syncthreads();

        if (kt < 15) {
            const float* ap = aptr + (kt + 1) * 64;
            const unsigned short* bp = bptr + (kt + 1) * 64;
#pragma unroll
            for (int r = 0; r < 4; ++r) ra[r] = ((const float4*)ap)[r];
            rb[0] = *(const uint4*)bp;
            rb[1] = *(const uint4*)(bp + 8);
        }

#pragma unroll
        for (int ks = 0; ks < 2; ++ks) {
            s8v a_frag[2], b_frag[2];
#pragma unroll
            for (int i = 0; i < 2; ++i)
                a_frag[i] = *(const s8v*)(As + (wave_m + 16 * i + lr) * 72 + ks * 32 + lq * 8);
#pragma unroll
            for (int j = 0; j < 2; ++j)
                b_frag[j] = *(const s8v*)(Bs + (wave_n + 16 * j + lr) * 72 + ks * 32 + lq * 8);
#pragma unroll
            for (int i = 0; i < 2; ++i)
#pragma unroll
                for (int j = 0; j < 2; ++j)
                    acc[i][j] = __builtin_amdgcn_mfma_f32_16x16x32_bf16(
                        a_frag[i], b_frag[j], acc[i][j], 0, 0, 0);
        }
    }
    __syncthreads();

    // transpose through LDS: cs[n_local][v_local]
#pragma unroll
    for (int i = 0; i < 2; ++i)
#pragma unroll
        for (int j = 0; j < 2; ++j)
#pragma unroll
            for (int reg = 0; reg < 4; ++reg)
                cs[(wave_n + 16 * j + lr) * 68 + wave_m + 16 * i + lq * 4 + reg] = acc[i][j][reg];
    __syncthreads();

    // coalesced stores + log-softmax partials
    const int n = tid >> 2, q = tid & 3;
    const int v0 = bm * 64 + q * 16;
    float4 vals[4];
    float m_loc = -1e30f;
#pragma unroll
    for (int k = 0; k < 4; ++k) {
        float4 cv = *(const float4*)(cs + n * 68 + q * 16 + 4 * k);
        float4 bv = *(const float4*)(h2ob + v0 + 4 * k);
        cv.x += bv.x; cv.y += bv.y; cv.z += bv.z; cv.w += bv.w;
        vals[k] = cv;
        *(float4*)(dlogits + (size_t)n * V + v0 + 4 * k) = cv;
        m_loc = fmaxf(m_loc, fmaxf(fmaxf(cv.x, cv.y), fmaxf(cv.z, cv.w)));
    }
    float s_loc = 0.f;
#pragma unroll
    for (int k = 0; k < 4; ++k) {
        s_loc += __expf(vals[k].x - m_loc) + __expf(vals[k].y - m_loc)
               + __expf(vals[k].z - m_loc) + __expf(vals[k].w - m_loc);
    }
    // combine the 4 q-lanes (adjacent lanes) of row n
    float m2 = fmaxf(m_loc, __shfl_xor(m_loc, 1, 64));
    m2 = fmaxf(m2, __shfl_xor(m2, 2, 64));
    s_loc *= __expf(m_loc - m2);
    float s2 = s_loc + __shfl_xor(s_loc, 1, 64);
    s2 += __shfl_xor(s2, 2, 64);
    if (q == 0) {
        pmax[(size_t)n * VT + bm] = m2;
        psum[(size_t)n * VT + bm] = s2;
    }
}

// ---------------------------------------------------------------------------
// K4b: combine per-block partials -> lse[n]. grid 64, block 256.
// ---------------------------------------------------------------------------
__global__ __launch_bounds__(256) void k_lse(
    const float* __restrict__ pmax, const float* __restrict__ psum,
    float* __restrict__ lse)
{
    __shared__ float rm[4], rs[4];
    const int n = blockIdx.x, t = threadIdx.x;
    float m0 = (t < VT) ? pmax[(size_t)n * VT + t] : -1e30f;
    float m1 = (t + 256 < VT) ? pmax[(size_t)n * VT + t + 256] : -1e30f;
    float mm = fmaxf(m0, m1);
#pragma unroll
    for (int off = 32; off > 0; off >>= 1) mm = fmaxf(mm, __shfl_xor(mm, off, 64));
    if ((t & 63) == 0) rm[t >> 6] = mm;
    __syncthreads();
    float m = fmaxf(fmaxf(rm[0], rm[1]), fmaxf(rm[2], rm[3]));

    float s = 0.f;
    if (t < VT)       s += psum[(size_t)n * VT + t] * __expf(m0 - m);
    if (t + 256 < VT) s += psum[(size_t)n * VT + t + 256] * __expf(m1 - m);
#pragma unroll
    for (int off = 32; off > 0; off >>= 1) s += __shfl_xor(s, off, 64);
    if ((t & 63) == 0) rs[t >> 6] = s;
    __syncthreads();
    if (t == 0) {
        float st = rs[0] + rs[1] + rs[2] + rs[3];
        lse[n] = m + __logf(st);
    }
}

// ---------------------------------------------------------------------------
// K4c: normalize logits in place. grid (32, 64), block 256, float4.
// ---------------------------------------------------------------------------
__global__ __launch_bounds__(256) void k_norm(
    float* __restrict__ dlogits, const float* __restrict__ lse)
{
    const int n = blockIdx.y;
    const int t4 = blockIdx.x * 256 + threadIdx.x;   // float4 index in row
    if (t4 >= V / 4) return;
    float s = lse[n];
    float4* p = (float4*)(dlogits + (size_t)n * V) + t4;
    float4 v = *p;
    v.x -= s; v.y -= s; v.z -= s; v.w -= s;
    *p = v;
}

// ---------------------------------------------------------------------------
extern "C" void kernel_launch(void* const* d_in, const int* in_sizes, int n_in,
                              void* d_out, int out_size, void* d_ws, size_t ws_size,
                              hipStream_t stream)
{
    const int* ids   = (const int*)d_in[0];
    const float* h   = (const float*)d_in[1];
    const float* c   = (const float*)d_in[2];
    const float* enc = (const float*)d_in[3];
    const unsigned char* mask = (const unsigned char*)d_in[4];
    const float* embW = (const float*)d_in[5];
    const float* w_ih = (const float*)d_in[6];
    const float* b_ih = (const float*)d_in[7];
    const float* w_hh = (const float*)d_in[8];
    const float* b_hh = (const float*)d_in[9];
    const float* Wh   = (const float*)d_in[10];
    const float* Ws   = (const float*)d_in[11];
    const float* av   = (const float*)d_in[12];
    const float* h2oW = (const float*)d_in[13];
    const float* h2ob = (const float*)d_in[14];

    float* out = (float*)d_out;
    float* ws = (float*)d_ws;
    // layout (floats):
    float* gates_p = ws;                          // 8*64*2048 = 1048576
    float* sproj   = ws + 1048576;                // 32768
    float* scorep  = ws + 1048576 + 32768;        // 65536
    unsigned short* xb = (unsigned short*)(ws + 1048576 + 32768 + 65536);  // 64x1024 bf16
    // pmax/psum/lse overlay the gates_p region (dead after k_lstm_pw)
    float* pmax = ws;                             // 64*500 = 32000
    float* psum = ws + 32000;                     // 32000
    float* lse  = ws + 64000;                     // 64

    k_gates<<<dim3(32, 8), 256, 0, stream>>>(ids, h, embW, w_ih, w_hh, gates_p);
    k_lstm_pw<<<128, 256, 0, stream>>>(gates_p, b_ih, b_hh, c, out, xb);
    k_sproj<<<128, 256, 0, stream>>>(out, Wh, sproj);
    k_score_gemm<<<dim3(128, 8), 256, 0, stream>>>(enc, Ws, sproj, av, scorep);
    k_softmax_ctx<<<64, 512, 0, stream>>>(scorep, mask, enc, xb);
    k_logits<<<VT, 256, 0, stream>>>(h2oW, xb, h2ob, out, pmax, psum);
    k_lse<<<64, 256, 0, stream>>>(pmax, psum, lse);
    k_norm<<<dim3(32, 64), 256, 0, stream>>>(out, lse);
}